// Round 13
// baseline (94.482 us; speedup 1.0000x reference)
//
#include <hip/hip_runtime.h>
#include <hip/hip_bf16.h>

// GraphAttentionLayer: out = elu( softmax_row( where(adj>0, lrelu(src_i+dst_j), 0) ) @ wh )
//
// R12 post-mortem: nt-removal -> 91.8us total, k2 ~75us (3.6 TB/s). Remaining
// 2x vs k0_pack's 37us/pass (same buffer, plain loads): k2's load instruction
// touches 16 lines x 64B-used; k0's touches 8 lines fully covered. Request-
// rate bound -> exactly 2x.
// R13: full-line adj geometry. Per instruction: 8 lanes x 16B contiguous per
// row x 8 rows = 8 fully-covered 128B lines. P computed in loader layout,
// routed to MFMA A-fragment layout via WAVE-PRIVATE Plds (16x64 bf16, stride
// 144B): intra-wave DS is in-order -> no new barriers. Depth-3 vmem pipeline,
// swizzled Blds, epilogue unchanged from R12 (proven).

constexpr int N_ROWS = 8192;
constexpr int F_IN   = 128;
constexpr int F_OUT  = 64;
#define LRELU_A 0.2f
#define LOG2E   1.4426950408889634f

// workspace layout (bytes)
constexpr size_t OFF_WHT  = 0;                    // 1 MiB bf16 [f][row]
constexpr size_t OFF_SRC  = 1048576;              // 8192 f32 (x log2e)
constexpr size_t OFF_DST  = OFF_SRC + 32768;      // 8192 f32 (x log2e)
constexpr size_t OFF_LP   = OFF_DST + 32768;      // S*8192 f32
constexpr size_t OFF_ACC  = OFF_LP + 16 * 32768;  // 16*8192*64 f32 = 32 MiB

typedef __attribute__((ext_vector_type(4))) float f32x4;
typedef __attribute__((ext_vector_type(4))) int   i32x4;
typedef __attribute__((ext_vector_type(4))) short s16x4;
typedef __attribute__((ext_vector_type(8))) short s16x8;

static __device__ __forceinline__ short f2bf(float f) {
  unsigned u = __float_as_uint(f);
  u = (u + 0x7fffu + ((u >> 16) & 1u)) >> 16;  // RNE
  return (short)u;
}

// ---------------- Kernel 1: wh = x@w ; src/dst (x log2e) ; whT (bf16) -------
__global__ __launch_bounds__(256) void k1_proj(
    const float* __restrict__ x, const float* __restrict__ w,
    const float* __restrict__ a, short* __restrict__ whT,
    float* __restrict__ src, float* __restrict__ dst)
{
  const int lane = threadIdx.x & 63;   // = output feature f
  const int wid  = threadIdx.x >> 6;
  const int rowBase = blockIdx.x * 32 + wid * 8;   // 8 rows per wave

  float acc[8];
#pragma unroll
  for (int r = 0; r < 8; ++r) acc[r] = 0.0f;

#pragma unroll 1
  for (int kc = 0; kc < 4; ++kc) {     // K chunks of 32 — ONE wreg live
    float wreg[32];
#pragma unroll
    for (int kk = 0; kk < 32; ++kk)
      wreg[kk] = w[(kc * 32 + kk) * F_OUT + lane];   // coalesced
#pragma unroll
    for (int r = 0; r < 8; ++r) {
      const f32x4* xp = (const f32x4*)(x + (size_t)(rowBase + r) * F_IN + kc * 32);
#pragma unroll
      for (int q = 0; q < 8; ++q) {    // wave-uniform broadcast loads
        f32x4 xv = xp[q];
        acc[r] = fmaf(xv.x, wreg[4*q+0], acc[r]);
        acc[r] = fmaf(xv.y, wreg[4*q+1], acc[r]);
        acc[r] = fmaf(xv.z, wreg[4*q+2], acc[r]);
        acc[r] = fmaf(xv.w, wreg[4*q+3], acc[r]);
      }
    }
  }

  s16x8 hb;
#pragma unroll
  for (int r = 0; r < 8; ++r) hb[r] = f2bf(acc[r]);
  *(s16x8*)&whT[(size_t)lane * N_ROWS + rowBase] = hb;

  const float aS = a[lane];
  const float aD = a[F_OUT + lane];
#pragma unroll
  for (int r = 0; r < 8; ++r) {
    float ts = acc[r] * aS;
    float td = acc[r] * aD;
#pragma unroll
    for (int off = 32; off > 0; off >>= 1) {
      ts += __shfl_xor(ts, off, 64);
      td += __shfl_xor(td, off, 64);
    }
    if (lane == 0) {
      src[rowBase + r] = ts * LOG2E;   // log2-domain scores
      dst[rowBase + r] = td * LOG2E;
    }
  }
}

// ---------------- Kernel 2: full-line adj, wave-private P redistribution ----
// grid: (N/64, S) x 256 threads (4 waves x 16 rows). No in-loop barriers.
// adj loads: 8 lanes x 16B contiguous per row x 8 rows = 8 full lines/instr.
template<int S>
__global__ __launch_bounds__(256, 2) void k2_attn(
    const int* __restrict__ adj, const short* __restrict__ whT,
    const float* __restrict__ src, const float* __restrict__ dst,
    float* __restrict__ acc_part, float* __restrict__ l_part)
{
  constexpr int JLEN = N_ROWS / S;   // 512
  constexpr int NI   = JLEN / 64;    // 8
  constexpr int PSTR = 144;          // P row stride bytes (16B-aligned pad)
  __shared__ short Blds[64 * JLEN];  // 64 KB, byte ^= (f&7)<<4 swizzle
  __shared__ float Dlds[JLEN];       // 2 KB
  __shared__ short Plds[4][16 * (PSTR / 2)];  // 4 x 2.25 KB wave-private

  const int tid  = threadIdx.x;
  const int lane = tid & 63;
  const int wid  = tid >> 6;
  const int s    = blockIdx.y;
  const int jbase = s * JLEN;
  const int rowg = blockIdx.x * 64 + wid * 16;
  const int r16  = lane & 15;
  const int kq   = lane >> 4;
  const int lg   = lane >> 3;        // loader row group 0..7
  const int lc   = lane & 7;         // loader col chunk 0..7

  // ---- stage B slice (swizzled) + dst slice; ONE barrier total ----
#pragma unroll
  for (int q = 0; q < 16; ++q) {         // 4096 x 16B chunks / 256 threads
    const int m   = tid + q * 256;
    const int f   = m >> 6;
    const int c16 = m & 63;
    const s16x8 v = *(const s16x8*)(whT + (size_t)f * N_ROWS + jbase + c16 * 8);
    *(s16x8*)((char*)Blds + f * (JLEN * 2) + ((c16 * 16) ^ ((f & 7) << 4))) = v;
  }
  if (tid < JLEN / 4)
    *(f32x4*)&Dlds[tid * 4] = *(const f32x4*)(dst + jbase + tid * 4);
  __syncthreads();

  // loader-layout bases: rows rowg+lg and rowg+8+lg, cols lc*4 within 64-block
  const size_t rbA = (size_t)(rowg + lg) * N_ROWS + jbase + lc * 4;
  const size_t rbB = rbA + (size_t)8 * N_ROWS;
  const float srcA = src[rowg + lg];          // already * log2e
  const float srcB = src[rowg + 8 + lg];
  const int cswz = (r16 & 7) << 4;
  char* const myP = (char*)&Plds[wid][0];

  f32x4 acc0 = {0,0,0,0}, acc1 = {0,0,0,0}, acc2 = {0,0,0,0}, acc3 = {0,0,0,0};
  float lpA = 0.0f, lpB = 0.0f;

  i32x4 A[3][4];   // depth-3 adj pipeline; [t]: t&1 row half, t>>1 col half

  auto issueAdj = [&](int b, int i) {
    A[b][0] = *(const i32x4*)(adj + rbA + i * 64);        // rows lg,   cols 0-31
    A[b][1] = *(const i32x4*)(adj + rbB + i * 64);        // rows 8+lg, cols 0-31
    A[b][2] = *(const i32x4*)(adj + rbA + i * 64 + 32);   // rows lg,   cols 32-63
    A[b][3] = *(const i32x4*)(adj + rbB + i * 64 + 32);   // rows 8+lg, cols 32-63
  };

  issueAdj(0, 0); issueAdj(1, 1); issueAdj(2, 2);   // prologue: depth 3

#pragma unroll
  for (int i = 0; i < NI; ++i) {     // FULL unroll: A[i%3] static
    const f32x4 d0 = *(const f32x4*)&Dlds[i * 64 + lc * 4];
    const f32x4 d1 = *(const f32x4*)&Dlds[i * 64 + 32 + lc * 4];
    // ---- phase A: compute P in loader layout, write wave-private Plds ----
#pragma unroll
    for (int t = 0; t < 4; ++t) {
      const i32x4 av = A[i % 3][t];
      const float sv = (t & 1) ? srcB : srcA;
      const f32x4 dd = (t >> 1) ? d1 : d0;
      float p0, p1, p2, p3;
#define PE(pp, dv, aa) { float e = sv + (dv); e = fmaxf(e, LRELU_A * e); \
                         (pp) = ((aa) > 0) ? __builtin_amdgcn_exp2f(e) : 1.0f; }
      PE(p0, dd.x, av.x) PE(p1, dd.y, av.y) PE(p2, dd.z, av.z) PE(p3, dd.w, av.w)
#undef PE
      if (t & 1) lpB += (p0 + p1) + (p2 + p3);
      else       lpA += (p0 + p1) + (p2 + p3);
      union { s16x4 v; __hip_bfloat16 b[4]; } u;
      u.b[0] = __float2bfloat16(p0); u.b[1] = __float2bfloat16(p1);
      u.b[2] = __float2bfloat16(p2); u.b[3] = __float2bfloat16(p3);
      const int prow = (t & 1) * 8 + lg;
      *(s16x4*)(myP + prow * PSTR + (t >> 1) * 64 + lc * 8) = u.v;
    }
    // ---- prefetch i+3 (newest vmem; stays in flight across waits) ----
    if (i + 3 < NI) issueAdj(i % 3, i + 3);
    // ---- phase B: A-fragment from wave-private Plds (in-order DS), MFMA ----
#pragma unroll
    for (int h = 0; h < 2; ++h) {
      const s16x8 af = *(const s16x8*)(myP + r16 * PSTR + h * 64 + kq * 16);
      const char* bb = (const char*)Blds;
      const int colb = (i * 64 + h * 32 + kq * 8) * 2;
      const s16x8 b0 = *(const s16x8*)(bb + (0 * 16 + r16) * (JLEN * 2) + (colb ^ cswz));
      const s16x8 b1 = *(const s16x8*)(bb + (1 * 16 + r16) * (JLEN * 2) + (colb ^ cswz));
      const s16x8 b2 = *(const s16x8*)(bb + (2 * 16 + r16) * (JLEN * 2) + (colb ^ cswz));
      const s16x8 b3 = *(const s16x8*)(bb + (3 * 16 + r16) * (JLEN * 2) + (colb ^ cswz));
      acc0 = __builtin_amdgcn_mfma_f32_16x16x32_bf16(af, b0, acc0, 0, 0, 0);
      acc1 = __builtin_amdgcn_mfma_f32_16x16x32_bf16(af, b1, acc1, 0, 0, 0);
      acc2 = __builtin_amdgcn_mfma_f32_16x16x32_bf16(af, b2, acc2, 0, 0, 0);
      acc3 = __builtin_amdgcn_mfma_f32_16x16x32_bf16(af, b3, acc3, 0, 0, 0);
    }
  }

  // ---- epilogue ----
  // lpA/lpB: partial sums for rows rowg+lg / rowg+8+lg, reduce over lc
  lpA += __shfl_xor(lpA, 1, 64); lpB += __shfl_xor(lpB, 1, 64);
  lpA += __shfl_xor(lpA, 2, 64); lpB += __shfl_xor(lpB, 2, 64);
  lpA += __shfl_xor(lpA, 4, 64); lpB += __shfl_xor(lpB, 4, 64);
  if (lc == 0) {
    l_part[(size_t)s * N_ROWS + rowg + lg]     = lpA;
    l_part[(size_t)s * N_ROWS + rowg + 8 + lg] = lpB;
  }

  // C/D layout: col(feat) = lane&15, row = (lane>>4)*4 + reg
#define STORE_ACC(av, nt) _Pragma("unroll") \
  for (int rg = 0; rg < 4; ++rg) { \
    const int row = rowg + kq * 4 + rg; \
    acc_part[((size_t)s * N_ROWS + row) * F_OUT + (nt) * 16 + r16] = (av)[rg]; \
  }
  STORE_ACC(acc0, 0) STORE_ACC(acc1, 1) STORE_ACC(acc2, 2) STORE_ACC(acc3, 3)
#undef STORE_ACC
}

// ---------------- Kernel 3: combine partials, normalize, ELU ----------------
template<int S>
__global__ __launch_bounds__(256) void k3_combine(
    const float* __restrict__ acc_part, const float* __restrict__ l_part,
    float* __restrict__ out)
{
  const int idx = blockIdx.x * 256 + threadIdx.x;  // over N*F/4
  const int row = idx >> 4;          // F_OUT/4 = 16
  const int f4  = idx & 15;
  f32x4 h = {0.f, 0.f, 0.f, 0.f};
  float l = 0.f;
#pragma unroll
  for (int s = 0; s < S; ++s) {
    h += *(const f32x4*)(acc_part + ((size_t)s * N_ROWS + row) * F_OUT + 4 * f4);
    l += l_part[(size_t)s * N_ROWS + row];
  }
  const float inv = 1.0f / l;
  f32x4 o;
  {
    float v0 = h.x * inv; o.x = v0 > 0.f ? v0 : (__expf(v0) - 1.0f);
    float v1 = h.y * inv; o.y = v1 > 0.f ? v1 : (__expf(v1) - 1.0f);
    float v2 = h.z * inv; o.z = v2 > 0.f ? v2 : (__expf(v2) - 1.0f);
    float v3 = h.w * inv; o.w = v3 > 0.f ? v3 : (__expf(v3) - 1.0f);
  }
  *(f32x4*)(out + (size_t)row * F_OUT + 4 * f4) = o;
}

// ---------------- launch ----------------
extern "C" void kernel_launch(void* const* d_in, const int* in_sizes, int n_in,
                              void* d_out, int out_size, void* d_ws, size_t ws_size,
                              hipStream_t stream) {
  const float* x   = (const float*)d_in[0];
  const int*   adj = (const int*)d_in[1];
  const float* w   = (const float*)d_in[2];
  const float* a   = (const float*)d_in[3];
  float* out = (float*)d_out;
  char* ws = (char*)d_ws;

  short* whT      = (short*)(ws + OFF_WHT);
  float* src      = (float*)(ws + OFF_SRC);
  float* dst      = (float*)(ws + OFF_DST);
  float* l_part   = (float*)(ws + OFF_LP);
  float* acc_part = (float*)(ws + OFF_ACC);

  k1_proj<<<N_ROWS / 32, 256, 0, stream>>>(x, w, a, whT, src, dst);
  k2_attn<16><<<dim3(N_ROWS / 64, 16), 256, 0, stream>>>(adj, whT, src, dst,
                                                         acc_part, l_part);
  k3_combine<16><<<(N_ROWS * F_OUT / 4) / 256, 256, 0, stream>>>(acc_part, l_part, out);
}